// Round 2
// baseline (2289.064 us; speedup 1.0000x reference)
//
#include <hip/hip_runtime.h>
#include <math.h>

// ---------------------------------------------------------------------------
// CSAttention forward, fp32, MI355X.
// Layout: all token maps stored (b, h*64+w, c) row-major, C=256, B=16.
// Workspace plan (floats), total ~55.8M floats = 223 MB:
//   blend  [16.78M]  persistent across scales
//   s1     [16.78M]  scale-1 (ws=4) proj output, feeds dlight
//   scr    [16.78M]  per-chunk Q(=ctx)/K/V during scales; reused as `up` later
//   edge/wts/xdl/axq/axk/axv/xg  [~5.5M]
// Chunking: 4 batches per chunk (16384 tokens) so Q/K/V are 16MB each.
// ---------------------------------------------------------------------------

#define CHUNK_B 4
#define CHUNK_TOK (CHUNK_B * 4096)   // 16384 tokens per chunk

// ---------------- fused 3-matrix GEMM: O_m = A @ W_m + b_m ------------------
__global__ __launch_bounds__(256) void gemm_qkv3(
    const float* __restrict__ A,
    const float* __restrict__ W0, const float* __restrict__ W1, const float* __restrict__ W2,
    const float* __restrict__ b0, const float* __restrict__ b1, const float* __restrict__ b2,
    float* __restrict__ O0, float* __restrict__ O1, float* __restrict__ O2)
{
    __shared__ float Ast[16][68];     // [kk][row] transposed A tile
    __shared__ float Bs[3][16][68];   // [m][kk][col]
    const int tid = threadIdx.x;
    const int tx = tid & 15, ty = tid >> 4;
    const int m0 = blockIdx.x * 64, n0 = blockIdx.y * 64;

    float acc[3][4][4];
#pragma unroll
    for (int m = 0; m < 3; m++)
#pragma unroll
        for (int i = 0; i < 4; i++)
#pragma unroll
            for (int j = 0; j < 4; j++) acc[m][i][j] = 0.f;

    const int ar = tid >> 2;          // 0..63
    const int ac = (tid & 3) * 4;     // 0,4,8,12
    const int bk = tid >> 4;          // 0..15
    const int bn = (tid & 15) * 4;    // 0..60
    const float* Ws[3] = {W0, W1, W2};

    for (int k0 = 0; k0 < 256; k0 += 16) {
        float4 av = *(const float4*)(A + (size_t)(m0 + ar) * 256 + k0 + ac);
        Ast[ac + 0][ar] = av.x; Ast[ac + 1][ar] = av.y;
        Ast[ac + 2][ar] = av.z; Ast[ac + 3][ar] = av.w;
#pragma unroll
        for (int m = 0; m < 3; m++) {
            float4 bv = *(const float4*)(Ws[m] + (size_t)(k0 + bk) * 256 + n0 + bn);
            *(float4*)&Bs[m][bk][bn] = bv;
        }
        __syncthreads();
#pragma unroll
        for (int kk = 0; kk < 16; kk++) {
            float4 a4 = *(const float4*)&Ast[kk][ty * 4];
            float a[4] = {a4.x, a4.y, a4.z, a4.w};
#pragma unroll
            for (int m = 0; m < 3; m++) {
                float4 b4 = *(const float4*)&Bs[m][kk][tx * 4];
                float bb[4] = {b4.x, b4.y, b4.z, b4.w};
#pragma unroll
                for (int i = 0; i < 4; i++)
#pragma unroll
                    for (int j = 0; j < 4; j++)
                        acc[m][i][j] = fmaf(a[i], bb[j], acc[m][i][j]);
            }
        }
        __syncthreads();
    }
    const float* bs[3] = {b0, b1, b2};
    float* Os[3] = {O0, O1, O2};
#pragma unroll
    for (int m = 0; m < 3; m++) {
        float bj[4];
#pragma unroll
        for (int j = 0; j < 4; j++) bj[j] = bs[m][n0 + tx * 4 + j];
#pragma unroll
        for (int i = 0; i < 4; i++) {
            const size_t row = m0 + ty * 4 + i;
            float4 o = make_float4(acc[m][i][0] + bj[0], acc[m][i][1] + bj[1],
                                   acc[m][i][2] + bj[2], acc[m][i][3] + bj[3]);
            *(float4*)(Os[m] + row * 256 + n0 + tx * 4) = o;
        }
    }
}

// ------------- out-projection GEMM with fused blend accumulate --------------
// A is chunk-local (rows 0..CHUNK_TOK); blend/s1/wts indexed by row+row_off.
__global__ __launch_bounds__(256) void gemm_proj(
    const float* __restrict__ A, const float* __restrict__ W, const float* __restrict__ bias,
    float* __restrict__ Sout, int store_s,
    float* __restrict__ Bl, const float* __restrict__ wts, int scale_idx, int blend_init,
    int row_off)
{
    __shared__ float Ast[16][68];
    __shared__ float Bs[16][68];
    const int tid = threadIdx.x;
    const int tx = tid & 15, ty = tid >> 4;
    const int m0 = blockIdx.x * 64, n0 = blockIdx.y * 64;

    float acc[4][4];
#pragma unroll
    for (int i = 0; i < 4; i++)
#pragma unroll
        for (int j = 0; j < 4; j++) acc[i][j] = 0.f;

    const int ar = tid >> 2;
    const int ac = (tid & 3) * 4;
    const int bk = tid >> 4;
    const int bn = (tid & 15) * 4;

    for (int k0 = 0; k0 < 256; k0 += 16) {
        float4 av = *(const float4*)(A + (size_t)(m0 + ar) * 256 + k0 + ac);
        Ast[ac + 0][ar] = av.x; Ast[ac + 1][ar] = av.y;
        Ast[ac + 2][ar] = av.z; Ast[ac + 3][ar] = av.w;
        float4 bv = *(const float4*)(W + (size_t)(k0 + bk) * 256 + n0 + bn);
        *(float4*)&Bs[bk][bn] = bv;
        __syncthreads();
#pragma unroll
        for (int kk = 0; kk < 16; kk++) {
            float4 a4 = *(const float4*)&Ast[kk][ty * 4];
            float a[4] = {a4.x, a4.y, a4.z, a4.w};
            float4 b4 = *(const float4*)&Bs[kk][tx * 4];
            float bb[4] = {b4.x, b4.y, b4.z, b4.w};
#pragma unroll
            for (int i = 0; i < 4; i++)
#pragma unroll
                for (int j = 0; j < 4; j++)
                    acc[i][j] = fmaf(a[i], bb[j], acc[i][j]);
        }
        __syncthreads();
    }
    float bj[4];
#pragma unroll
    for (int j = 0; j < 4; j++) bj[j] = bias[n0 + tx * 4 + j];
#pragma unroll
    for (int i = 0; i < 4; i++) {
        const size_t grow = (size_t)row_off + m0 + ty * 4 + i;
        const float wt = wts[grow * 3 + scale_idx];
        float v[4];
#pragma unroll
        for (int j = 0; j < 4; j++) v[j] = acc[i][j] + bj[j];
        if (store_s) {
            float4 o = make_float4(v[0], v[1], v[2], v[3]);
            *(float4*)(Sout + grow * 256 + n0 + tx * 4) = o;
        }
        float* bp = Bl + grow * 256 + n0 + tx * 4;
        if (blend_init) {
            float4 o = make_float4(wt * v[0], wt * v[1], wt * v[2], wt * v[3]);
            *(float4*)bp = o;
        } else {
            float4 old = *(const float4*)bp;
            float4 o = make_float4(old.x + wt * v[0], old.y + wt * v[1],
                                   old.z + wt * v[2], old.w + wt * v[3]);
            *(float4*)bp = o;
        }
    }
}

// --------- final squeeze: OUT = [UP | BL] @ sq_w^T + sq_b  (K=512) ----------
__global__ __launch_bounds__(256) void gemm_final(
    const float* __restrict__ UP, const float* __restrict__ BL,
    const float* __restrict__ SQW, const float* __restrict__ SQB,
    float* __restrict__ OUT)
{
    __shared__ float Ast[16][68];
    __shared__ float Bs[16][68];
    const int tid = threadIdx.x;
    const int tx = tid & 15, ty = tid >> 4;
    const int m0 = blockIdx.x * 64, n0 = blockIdx.y * 64;

    float acc[4][4];
#pragma unroll
    for (int i = 0; i < 4; i++)
#pragma unroll
        for (int j = 0; j < 4; j++) acc[i][j] = 0.f;

    const int ar = tid >> 2;
    const int ac = (tid & 3) * 4;
    const int bn_ = tid >> 2;        // 0..63 col for B load
    const int bk4 = (tid & 3) * 4;   // 0..12

    for (int k0 = 0; k0 < 512; k0 += 16) {
        const float* Asrc = (k0 < 256) ? UP : BL;
        const int kc = k0 & 255;
        float4 av = *(const float4*)(Asrc + (size_t)(m0 + ar) * 256 + kc + ac);
        Ast[ac + 0][ar] = av.x; Ast[ac + 1][ar] = av.y;
        Ast[ac + 2][ar] = av.z; Ast[ac + 3][ar] = av.w;
        // B[k][n] = SQW[n*512 + k]  (transposed load)
        float4 bv = *(const float4*)(SQW + (size_t)(n0 + bn_) * 512 + k0 + bk4);
        Bs[bk4 + 0][bn_] = bv.x; Bs[bk4 + 1][bn_] = bv.y;
        Bs[bk4 + 2][bn_] = bv.z; Bs[bk4 + 3][bn_] = bv.w;
        __syncthreads();
#pragma unroll
        for (int kk = 0; kk < 16; kk++) {
            float4 a4 = *(const float4*)&Ast[kk][ty * 4];
            float a[4] = {a4.x, a4.y, a4.z, a4.w};
            float4 b4 = *(const float4*)&Bs[kk][tx * 4];
            float bb[4] = {b4.x, b4.y, b4.z, b4.w};
#pragma unroll
            for (int i = 0; i < 4; i++)
#pragma unroll
                for (int j = 0; j < 4; j++)
                    acc[i][j] = fmaf(a[i], bb[j], acc[i][j]);
        }
        __syncthreads();
    }
    float bj[4];
#pragma unroll
    for (int j = 0; j < 4; j++) bj[j] = SQB[n0 + tx * 4 + j];
#pragma unroll
    for (int i = 0; i < 4; i++) {
        const size_t row = m0 + ty * 4 + i;
        float4 o = make_float4(acc[i][0] + bj[0], acc[i][1] + bj[1],
                               acc[i][2] + bj[2], acc[i][3] + bj[3]);
        *(float4*)(OUT + row * 256 + n0 + tx * 4) = o;
    }
}

// ----------------- windowed multi-head attention (per window) ---------------
// Works on a chunk of CHUNK_B batches; b is chunk-local.
// grid.x = CHUNK_B*(64/WS)^2, grid.y = 8/NH
template <int WS, int NH>
__global__ __launch_bounds__(256) void win_attn(
    const float* __restrict__ Q, const float* __restrict__ K,
    const float* __restrict__ V, float* __restrict__ CTX)
{
    constexpr int WIN = WS * WS;
    constexpr int NW = 64 / WS;
    constexpr int CW = NH * 32;
    __shared__ float qs[WIN][CW + 4], ks[WIN][CW + 4], vs[WIN][CW + 4];
    __shared__ float sc[NH][WIN][WIN + 1];
    const int tid = threadIdx.x;
    const int wid = blockIdx.x;
    const int b = wid / (NW * NW);
    const int rem = wid % (NW * NW);
    const int p = rem / NW, q = rem % NW;
    const int h0 = blockIdx.y * NH;

    for (int idx = tid; idx < WIN * CW; idx += 256) {
        const int i = idx / CW;
        const int cc = idx % CW;
        const int ti = i / WS, tj = i % WS;
        const size_t g = ((size_t)(b * 4096 + (p * WS + ti) * 64 + (q * WS + tj))) * 256 + h0 * 32 + cc;
        qs[i][cc] = Q[g]; ks[i][cc] = K[g]; vs[i][cc] = V[g];
    }
    __syncthreads();
    const float scale = 0.17677669529663687f;  // 1/sqrt(32)
    for (int idx = tid; idx < NH * WIN * WIN; idx += 256) {
        const int hl = idx / (WIN * WIN);
        const int r = idx % (WIN * WIN);
        const int i = r / WIN, j = r % WIN;
        const int co = hl * 32;
        float s = 0.f;
#pragma unroll
        for (int d = 0; d < 32; d++) s += qs[i][co + d] * ks[j][co + d];
        sc[hl][i][j] = s * scale;
    }
    __syncthreads();
    if (tid < NH * WIN) {
        const int hl = tid / WIN, i = tid % WIN;
        float mx = -3.4e38f;
        for (int j = 0; j < WIN; j++) mx = fmaxf(mx, sc[hl][i][j]);
        float sum = 0.f;
        for (int j = 0; j < WIN; j++) {
            float e = __expf(sc[hl][i][j] - mx);
            sc[hl][i][j] = e; sum += e;
        }
        const float inv = 1.f / sum;
        for (int j = 0; j < WIN; j++) sc[hl][i][j] *= inv;
    }
    __syncthreads();
    // CTX may alias Q: all Q reads completed before this point (LDS staged).
    for (int idx = tid; idx < WIN * CW; idx += 256) {
        const int i = idx / CW;
        const int cc = idx % CW;
        const int hl = cc >> 5;
        float s = 0.f;
        for (int j = 0; j < WIN; j++) s += sc[hl][i][j] * vs[j][cc];
        const int ti = i / WS, tj = i % WS;
        const size_t g = ((size_t)(b * 4096 + (p * WS + ti) * 64 + (q * WS + tj))) * 256 + h0 * 32 + cc;
        CTX[g] = s;
    }
}

// ----------------------------- edge conv (C->1, 3x3) ------------------------
__global__ __launch_bounds__(256) void edge_conv(
    const float* __restrict__ x, const float* __restrict__ ew, float* __restrict__ edge)
{
    __shared__ float wsm[2304];
    __shared__ float red[4];
    const int bh = blockIdx.x;
    const int b = bh >> 6, h = bh & 63;
    const int tid = threadIdx.x;  // = channel
    for (int i = tid; i < 2304; i += 256) wsm[i] = ew[i];
    __syncthreads();
    float wc[9];
#pragma unroll
    for (int t = 0; t < 9; t++) wc[t] = wsm[tid * 9 + t];

    for (int w = 0; w < 64; w++) {
        float acc = 0.f;
#pragma unroll
        for (int kh = 0; kh < 3; kh++) {
            const int hh = h + kh - 1;
            if ((unsigned)hh > 63u) continue;
#pragma unroll
            for (int kw = 0; kw < 3; kw++) {
                const int ww = w + kw - 1;
                if ((unsigned)ww > 63u) continue;
                acc += x[((size_t)b * 4096 + hh * 64 + ww) * 256 + tid] * wc[kh * 3 + kw];
            }
        }
        for (int off = 32; off; off >>= 1) acc += __shfl_down(acc, off);
        if ((tid & 63) == 0) red[tid >> 6] = acc;
        __syncthreads();
        if (tid == 0)
            edge[(size_t)b * 4096 + h * 64 + w] = fabsf(red[0] + red[1] + red[2] + red[3]);
        __syncthreads();
    }
}

// ---------------- box-average + tiny MLP + 3-way softmax --------------------
__global__ __launch_bounds__(256) void avg_mlp(
    const float* __restrict__ edge, const float* __restrict__ w1, const float* __restrict__ b1,
    const float* __restrict__ w2, const float* __restrict__ b2, float* __restrict__ wts)
{
    const int idx = blockIdx.x * 256 + threadIdx.x;  // 0..65535
    const int b = idx >> 12, rem = idx & 4095, h = rem >> 6, w = rem & 63;
    float s = 0.f;
#pragma unroll
    for (int kh = -1; kh <= 1; kh++) {
        const int hh = h + kh;
        if ((unsigned)hh > 63u) continue;
#pragma unroll
        for (int kw = -1; kw <= 1; kw++) {
            const int ww = w + kw;
            if ((unsigned)ww > 63u) continue;
            s += edge[(size_t)b * 4096 + hh * 64 + ww];
        }
    }
    const float e = s / 9.f;
    float l0 = b2[0], l1 = b2[1], l2 = b2[2];
#pragma unroll
    for (int j = 0; j < 16; j++) {
        float hd = fmaxf(e * w1[j] + b1[j], 0.f);
        l0 += hd * w2[j * 3 + 0];
        l1 += hd * w2[j * 3 + 1];
        l2 += hd * w2[j * 3 + 2];
    }
    const float mx = fmaxf(l0, fmaxf(l1, l2));
    const float e0 = __expf(l0 - mx), e1 = __expf(l1 - mx), e2 = __expf(l2 - mx);
    const float inv = 1.f / (e0 + e1 + e2);
    wts[(size_t)idx * 3 + 0] = e0 * inv;
    wts[(size_t)idx * 3 + 1] = e1 * inv;
    wts[(size_t)idx * 3 + 2] = e2 * inv;
}

// ---------------------- DlightConv token pooling ----------------------------
__global__ __launch_bounds__(256) void dlight(
    const float* __restrict__ S1, const float* __restrict__ dlw,
    const float* __restrict__ dlb, float* __restrict__ XDL)
{
    __shared__ float xw[16][257];
    __shared__ float m[256];
    __shared__ float pr[16];
    __shared__ float pr2[16];
    const int wid = blockIdx.x;  // b*256 + p*16 + q
    const int b = wid >> 8, rem = wid & 255, p = rem >> 4, q = rem & 15;
    const int tid = threadIdx.x;  // channel
#pragma unroll
    for (int t = 0; t < 16; t++) {
        const int ti = t >> 2, tj = t & 3;
        xw[t][tid] = S1[((size_t)b * 4096 + (p * 4 + ti) * 64 + (q * 4 + tj)) * 256 + tid];
    }
    float mm = 0.f;
#pragma unroll
    for (int t = 0; t < 16; t++) mm += xw[t][tid];
    m[tid] = mm * (1.f / 16.f);
    __syncthreads();
    if (tid < 16) {
        float lg = dlb[tid];
        for (int c = 0; c < 256; c++) lg += m[c] * dlw[c * 16 + tid];
        pr[tid] = lg;
    }
    __syncthreads();
    if (tid < 16) {
        float mx = -3.4e38f;
        for (int j = 0; j < 16; j++) mx = fmaxf(mx, pr[j]);
        float sum = 0.f;
        for (int j = 0; j < 16; j++) sum += __expf(pr[j] - mx);
        pr2[tid] = __expf(pr[tid] - mx) / sum;
    }
    __syncthreads();
    float o = 0.f;
#pragma unroll
    for (int t = 0; t < 16; t++) o += xw[t][tid] * pr2[t];
    XDL[(size_t)wid * 256 + tid] = o;
}

// ----------------------------- axial attention ------------------------------
__global__ __launch_bounds__(256) void axial_row(
    const float* __restrict__ Q, const float* __restrict__ K, const float* __restrict__ V,
    const float* __restrict__ gsp, const float* __restrict__ gbp, float* __restrict__ XG)
{
    __shared__ float qs[16][257], ks[16][257], vs[16][257];
    __shared__ float sc[16][17];
    const int bid = blockIdx.x;
    const int b = bid >> 4, r = bid & 15;
    const int tid = threadIdx.x;
    const float gs = gsp[0], gb = gbp[0];
#pragma unroll
    for (int w = 0; w < 16; w++) {
        const size_t base = ((size_t)b * 256 + r * 16 + w) * 256 + tid;
        qs[w][tid] = Q[base]; ks[w][tid] = K[base]; vs[w][tid] = V[base];
    }
    __syncthreads();
    {
        const int w = tid >> 4, vv = tid & 15;
        float s = 0.f;
        for (int c = 0; c < 256; c++) s += qs[w][c] * ks[vv][c];
        const float d = (float)(w - vv);
        sc[w][vv] = s - (gs * d * d + gb);
    }
    __syncthreads();
    if (tid < 16) {
        float mx = -3.4e38f;
        for (int j = 0; j < 16; j++) mx = fmaxf(mx, sc[tid][j]);
        float sum = 0.f;
        for (int j = 0; j < 16; j++) {
            float e = __expf(sc[tid][j] - mx);
            sc[tid][j] = e; sum += e;
        }
        const float inv = 1.f / sum;
        for (int j = 0; j < 16; j++) sc[tid][j] *= inv;
    }
    __syncthreads();
#pragma unroll
    for (int w2 = 0; w2 < 16; w2++) {
        float o = 0.f;
#pragma unroll
        for (int k2 = 0; k2 < 16; k2++) o += sc[w2][k2] * vs[k2][tid];
        XG[((size_t)b * 256 + r * 16 + w2) * 256 + tid] = o;
    }
}

__global__ __launch_bounds__(256) void axial_col(
    const float* __restrict__ Q, const float* __restrict__ K, const float* __restrict__ V,
    const float* __restrict__ gsp, const float* __restrict__ gbp, float* __restrict__ XG)
{
    __shared__ float qs[16][257], ks[16][257], vs[16][257];
    __shared__ float sc[16][17];
    const int bid = blockIdx.x;
    const int b = bid >> 4, col = bid & 15;
    const int tid = threadIdx.x;
    const float gs = gsp[0], gb = gbp[0];
#pragma unroll
    for (int h = 0; h < 16; h++) {
        const size_t base = ((size_t)b * 256 + h * 16 + col) * 256 + tid;
        qs[h][tid] = Q[base]; ks[h][tid] = K[base]; vs[h][tid] = V[base];
    }
    __syncthreads();
    {
        const int r = tid >> 4, vv = tid & 15;
        float s = 0.f;
        for (int c = 0; c < 256; c++) s += qs[r][c] * ks[vv][c];
        const float d = (float)(r - vv);
        sc[r][vv] = s - (gs * d * d + gb);
    }
    __syncthreads();
    if (tid < 16) {
        float mx = -3.4e38f;
        for (int j = 0; j < 16; j++) mx = fmaxf(mx, sc[tid][j]);
        float sum = 0.f;
        for (int j = 0; j < 16; j++) {
            float e = __expf(sc[tid][j] - mx);
            sc[tid][j] = e; sum += e;
        }
        const float inv = 1.f / sum;
        for (int j = 0; j < 16; j++) sc[tid][j] *= inv;
    }
    __syncthreads();
#pragma unroll
    for (int r2 = 0; r2 < 16; r2++) {
        float o = 0.f;
#pragma unroll
        for (int k2 = 0; k2 < 16; k2++) o += sc[r2][k2] * vs[k2][tid];
        XG[((size_t)b * 256 + r2 * 16 + col) * 256 + tid] += o;
    }
}

// -------------------- bilinear upsample 16x16 -> 64x64 ----------------------
__global__ __launch_bounds__(256) void upsample(
    const float* __restrict__ XG, float* __restrict__ UP)
{
    const unsigned idx = blockIdx.x * 256u + threadIdx.x;  // < 16777216
    const int c = idx & 255;
    const unsigned t2 = idx >> 8;
    const int w = t2 & 63;
    const unsigned t3 = t2 >> 6;
    const int h = t3 & 63;
    const int b = t3 >> 6;
    const float rr = 15.f / 63.f;
    const float ph = h * rr, pw = w * rr;
    int h0 = (int)floorf(ph); float th = ph - (float)h0; int h1 = min(h0 + 1, 15);
    int w0 = (int)floorf(pw); float tw = pw - (float)w0; int w1 = min(w0 + 1, 15);
    const size_t bb = (size_t)b * 256;
    const float v00 = XG[((bb + h0 * 16 + w0)) * 256 + c];
    const float v10 = XG[((bb + h1 * 16 + w0)) * 256 + c];
    const float v01 = XG[((bb + h0 * 16 + w1)) * 256 + c];
    const float v11 = XG[((bb + h1 * 16 + w1)) * 256 + c];
    const float c0 = v00 * (1.f - th) + v10 * th;
    const float c1 = v01 * (1.f - th) + v11 * th;
    UP[idx] = c0 * (1.f - tw) + c1 * tw;
}

// ---------------------------------------------------------------------------
extern "C" void kernel_launch(void* const* d_in, const int* in_sizes, int n_in,
                              void* d_out, int out_size, void* d_ws, size_t ws_size,
                              hipStream_t stream)
{
    const float* x      = (const float*)d_in[0];
    const float* attn_w = (const float*)d_in[1];
    const float* attn_b = (const float*)d_in[2];
    const float* edge_w = (const float*)d_in[3];
    const float* mlp_w1 = (const float*)d_in[4];
    const float* mlp_b1 = (const float*)d_in[5];
    const float* mlp_w2 = (const float*)d_in[6];
    const float* mlp_b2 = (const float*)d_in[7];
    const float* dl_w   = (const float*)d_in[8];
    const float* dl_b   = (const float*)d_in[9];
    const float* ax_w   = (const float*)d_in[10];
    const float* ax_b   = (const float*)d_in[11];
    const float* g_shift= (const float*)d_in[12];
    const float* g_bias = (const float*)d_in[13];
    const float* sq_w   = (const float*)d_in[14];
    const float* sq_b   = (const float*)d_in[15];
    float* out = (float*)d_out;

    float* ws = (float*)d_ws;
    const size_t MT = 65536;                 // total tokens
    float* blend = ws;                       // 16,777,216
    float* s1    = blend + MT * 256;         // 16,777,216
    float* scr   = s1 + MT * 256;            // 16,777,216 (chunk QKV; later `up`)
    float* chQ   = scr;                      //  4,194,304 (also ctx)
    float* chK   = chQ + (size_t)CHUNK_TOK * 256;
    float* chV   = chK + (size_t)CHUNK_TOK * 256;
    float* up    = scr;                      // reuse whole scr region later
    float* edge  = scr + MT * 256;           // 65,536
    float* wts   = edge + 65536;             // 196,608
    float* xdl   = wts + 196608;             // 1,048,576
    float* axq   = xdl + 1048576;            // 1,048,576
    float* axk   = axq + 1048576;            // 1,048,576
    float* axv   = axk + 1048576;            // 1,048,576
    float* xg    = axv + 1048576;            // 1,048,576
    // total: 55,836,672 floats = 223.3 MB <= ws_size (assumed)

    // selector weights (needed before first out-proj blend)
    edge_conv<<<1024, 256, 0, stream>>>(x, edge_w, edge);
    avg_mlp<<<256, 256, 0, stream>>>(edge, mlp_w1, mlp_b1, mlp_w2, mlp_b2, wts);

    // three window-attention scales, chunked over batches; blend fused in proj
    for (int i = 0; i < 3; i++) {
        const float* W0 = attn_w + (size_t)(i * 4 + 0) * 65536;
        const float* W1 = attn_w + (size_t)(i * 4 + 1) * 65536;
        const float* W2 = attn_w + (size_t)(i * 4 + 2) * 65536;
        const float* W3 = attn_w + (size_t)(i * 4 + 3) * 65536;
        const float* c0 = attn_b + (size_t)(i * 4 + 0) * 256;
        const float* c1 = attn_b + (size_t)(i * 4 + 1) * 256;
        const float* c2 = attn_b + (size_t)(i * 4 + 2) * 256;
        const float* c3 = attn_b + (size_t)(i * 4 + 3) * 256;
        for (int ch = 0; ch < 16 / CHUNK_B; ch++) {
            const size_t toff = (size_t)ch * CHUNK_TOK;
            const float* xc = x + toff * 256;
            gemm_qkv3<<<dim3(CHUNK_TOK / 64, 4), 256, 0, stream>>>(
                xc, W0, W1, W2, c0, c1, c2, chQ, chK, chV);
            if (i == 0)
                win_attn<2, 8><<<dim3(CHUNK_B * 32 * 32, 1), 256, 0, stream>>>(chQ, chK, chV, chQ);
            if (i == 1)
                win_attn<4, 4><<<dim3(CHUNK_B * 16 * 16, 2), 256, 0, stream>>>(chQ, chK, chV, chQ);
            if (i == 2)
                win_attn<8, 1><<<dim3(CHUNK_B * 8 * 8, 8), 256, 0, stream>>>(chQ, chK, chV, chQ);
            gemm_proj<<<dim3(CHUNK_TOK / 64, 4), 256, 0, stream>>>(
                chQ, W3, c3, s1, (i == 1) ? 1 : 0,
                blend, wts, i, (i == 0) ? 1 : 0, (int)toff);
        }
    }

    // DlightConv pooling on s1 (windowed view via index math)
    dlight<<<4096, 256, 0, stream>>>(s1, dl_w, dl_b, xdl);

    // axial q,k,v projections  (M = 4096 tokens)
    gemm_qkv3<<<dim3(64, 4), 256, 0, stream>>>(xdl, ax_w, ax_w + 65536, ax_w + 131072,
                                               ax_b, ax_b + 256, ax_b + 512,
                                               axq, axk, axv);
    axial_row<<<256, 256, 0, stream>>>(axq, axk, axv, g_shift, g_bias, xg);
    axial_col<<<256, 256, 0, stream>>>(axq, axk, axv, g_shift, g_bias, xg);

    // upsample 16x16 -> 64x64 into reused scr region (QKV chunks dead)
    upsample<<<65536, 256, 0, stream>>>(xg, up);

    // final squeeze GEMM
    gemm_final<<<dim3(1024, 4), 256, 0, stream>>>(up, blend, sq_w, sq_b, out);
}

// Round 4
// 1409.052 us; speedup vs baseline: 1.6245x; 1.6245x over previous
//
#include <hip/hip_runtime.h>
#include <math.h>

// ---------------------------------------------------------------------------
// CSAttention forward, MI355X. GEMMs via split-bf16 (hi/lo) 3-MFMA emulation:
//   A*B ~= Ah*Bh + Al*Bh + Ah*Bl   (fp32 accumulate, ~16 mantissa bits)
// Layout: token maps (b, h*64+w, c) row-major, C=256, B=16.
// R3 bugfix: STAGE_B staged only 8/16 ushorts per thread -> half of B tile
// was uninitialized LDS -> bf16 NaNs. Now stages full 16 elements.
// ---------------------------------------------------------------------------

#define CHUNK_B 4
#define CHUNK_TOK (CHUNK_B * 4096)   // 16384 tokens per chunk
#define SA 40                        // LDS k-stride (elements), 80B padded

typedef __attribute__((ext_vector_type(8))) short short8;
typedef __attribute__((ext_vector_type(4))) float f32x4;

__device__ __forceinline__ ushort f2bf(float f) {
    union { float f; unsigned u; } v; v.f = f;
    unsigned r = v.u + 0x7fff + ((v.u >> 16) & 1);
    return (ushort)(r >> 16);
}
__device__ __forceinline__ float bf2f(ushort h) {
    union { unsigned u; float f; } v; v.u = ((unsigned)h) << 16; return v.f;
}
__device__ __forceinline__ void split2(float v, ushort& h, ushort& l) {
    h = f2bf(v);
    l = f2bf(v - bf2f(h));
}

// ---------------- weight pre-split kernels ---------------------------------
// k-major source: W[mat][k][n] (256x256 each) -> Th/Tl[mat*65536 + n*256 + k]
__global__ __launch_bounds__(256) void split_w_kmajor(
    const float* __restrict__ W, ushort* __restrict__ Th, ushort* __restrict__ Tl, int nmats)
{
    const int idx = blockIdx.x * 256 + threadIdx.x;
    if (idx >= nmats * 65536) return;
    const int mat = idx >> 16, r = idx & 65535;
    const int n = r >> 8, k = r & 255;
    const float v = W[(size_t)mat * 65536 + k * 256 + n];
    ushort h, l; split2(v, h, l);
    Th[idx] = h; Tl[idx] = l;
}
// n-major source (sq_w is [n=256][k=512] already): straight copy-split
__global__ __launch_bounds__(256) void split_w_nmajor(
    const float* __restrict__ W, ushort* __restrict__ Th, ushort* __restrict__ Tl, int total)
{
    const int idx = blockIdx.x * 256 + threadIdx.x;
    if (idx >= total) return;
    ushort h, l; split2(W[idx], h, l);
    Th[idx] = h; Tl[idx] = l;
}

// ---------------- MFMA GEMM core pieces (macros for reuse) -----------------
// Tile: 128x128, BK=32, 4 waves (2x2 of 64x64), 16x16x32 bf16 MFMA.

#define GEMM_DECLS                                                            \
    __shared__ ushort Ah[128 * SA], Al[128 * SA], Bh[128 * SA], Bl[128 * SA]; \
    const int tid = threadIdx.x;                                              \
    const int wave = tid >> 6, lane = tid & 63;                               \
    const int quad = lane >> 4, l16 = lane & 15;                              \
    const int wr = (wave >> 1) * 64, wc = (wave & 1) * 64;                    \
    f32x4 acc[4][4];                                                          \
    _Pragma("unroll") for (int i = 0; i < 4; i++)                             \
        _Pragma("unroll") for (int j = 0; j < 4; j++)                         \
            acc[i][j] = (f32x4){0.f, 0.f, 0.f, 0.f};                          \
    const int srow = tid >> 1;            /* 0..127 */                        \
    const int skp  = (tid & 1) * 16;      /* 0 or 16 */

#define STAGE_A(Aptr, kk)                                                     \
    {                                                                         \
        const float* src = (Aptr) + (size_t)(m0 + srow) * 256 + (kk) + skp;   \
        _Pragma("unroll") for (int c = 0; c < 4; c++) {                       \
            float4 v = *(const float4*)(src + c * 4);                         \
            ushort4 h, l;                                                     \
            split2(v.x, h.x, l.x); split2(v.y, h.y, l.y);                     \
            split2(v.z, h.z, l.z); split2(v.w, h.w, l.w);                     \
            *(ushort4*)&Ah[srow * SA + skp + c * 4] = h;                      \
            *(ushort4*)&Al[srow * SA + skp + c * 4] = l;                      \
        }                                                                     \
    }

// Stage 16 ushorts per thread per buffer (two 16B vectors) -- full coverage.
#define STAGE_B(WthP, WtlP, Kst, k0)                                          \
    {                                                                         \
        const size_t wo = (size_t)(srow) * (Kst) + (k0) + skp;                \
        *(ulonglong2*)&Bh[srow * SA + skp]     = *(const ulonglong2*)((WthP) + wo);     \
        *(ulonglong2*)&Bh[srow * SA + skp + 8] = *(const ulonglong2*)((WthP) + wo + 8); \
        *(ulonglong2*)&Bl[srow * SA + skp]     = *(const ulonglong2*)((WtlP) + wo);     \
        *(ulonglong2*)&Bl[srow * SA + skp + 8] = *(const ulonglong2*)((WtlP) + wo + 8); \
    }

#define GEMM_COMPUTE                                                          \
    {                                                                         \
        short8 afh[4], afl[4], bfh[4], bfl[4];                                \
        _Pragma("unroll") for (int i = 0; i < 4; i++) {                       \
            const int ro = (wr + i * 16 + l16) * SA + quad * 8;               \
            afh[i] = *(const short8*)&Ah[ro];                                 \
            afl[i] = *(const short8*)&Al[ro];                                 \
        }                                                                     \
        _Pragma("unroll") for (int j = 0; j < 4; j++) {                       \
            const int no = (wc + j * 16 + l16) * SA + quad * 8;               \
            bfh[j] = *(const short8*)&Bh[no];                                 \
            bfl[j] = *(const short8*)&Bl[no];                                 \
        }                                                                     \
        _Pragma("unroll") for (int i = 0; i < 4; i++)                         \
            _Pragma("unroll") for (int j = 0; j < 4; j++) {                   \
                acc[i][j] = __builtin_amdgcn_mfma_f32_16x16x32_bf16(          \
                    afh[i], bfh[j], acc[i][j], 0, 0, 0);                      \
                acc[i][j] = __builtin_amdgcn_mfma_f32_16x16x32_bf16(          \
                    afl[i], bfh[j], acc[i][j], 0, 0, 0);                      \
                acc[i][j] = __builtin_amdgcn_mfma_f32_16x16x32_bf16(          \
                    afh[i], bfl[j], acc[i][j], 0, 0, 0);                      \
            }                                                                 \
    }

// ---------- fused 3-matrix GEMM (Q,K,V or axial q,k,v): grid (M/128, 6) -----
__global__ __launch_bounds__(256, 2) void gemm3_mfma(
    const float* __restrict__ A,
    const ushort* __restrict__ Wth, const ushort* __restrict__ Wtl,  // [3][256][256]
    const float* __restrict__ b0, const float* __restrict__ b1, const float* __restrict__ b2,
    float* __restrict__ O0, float* __restrict__ O1, float* __restrict__ O2)
{
    const int m0 = blockIdx.x * 128;
    const int mat = blockIdx.y >> 1;
    const int col0 = (blockIdx.y & 1) * 128;
    const ushort* wth = Wth + (size_t)mat * 65536 + (size_t)col0 * 256;
    const ushort* wtl = Wtl + (size_t)mat * 65536 + (size_t)col0 * 256;
    GEMM_DECLS
    for (int k0 = 0; k0 < 256; k0 += 32) {
        STAGE_A(A, k0)
        STAGE_B(wth, wtl, 256, k0)
        __syncthreads();
        GEMM_COMPUTE
        __syncthreads();
    }
    const float* bias = (mat == 0) ? b0 : (mat == 1) ? b1 : b2;
    float* O = (mat == 0) ? O0 : (mat == 1) ? O1 : O2;
#pragma unroll
    for (int j = 0; j < 4; j++) {
        const int col = col0 + wc + j * 16 + l16;
        const float bj = bias[col];
#pragma unroll
        for (int i = 0; i < 4; i++) {
            const int rbase = m0 + wr + i * 16 + quad * 4;
#pragma unroll
            for (int r = 0; r < 4; r++)
                O[(size_t)(rbase + r) * 256 + col] = acc[i][j][r] + bj;
        }
    }
}

// ---------- out-projection GEMM with fused blend: grid (M/128, 2) -----------
__global__ __launch_bounds__(256, 2) void gemmp_mfma(
    const float* __restrict__ A,
    const ushort* __restrict__ Wth, const ushort* __restrict__ Wtl,  // [256][256]
    const float* __restrict__ bias,
    float* __restrict__ Sout, int store_s,
    float* __restrict__ Blnd, const float* __restrict__ wts, int scale_idx, int blend_init,
    int row_off)
{
    const int m0 = blockIdx.x * 128;
    const int col0 = blockIdx.y * 128;
    const ushort* wth = Wth + (size_t)col0 * 256;
    const ushort* wtl = Wtl + (size_t)col0 * 256;
    GEMM_DECLS
    for (int k0 = 0; k0 < 256; k0 += 32) {
        STAGE_A(A, k0)
        STAGE_B(wth, wtl, 256, k0)
        __syncthreads();
        GEMM_COMPUTE
        __syncthreads();
    }
#pragma unroll
    for (int i = 0; i < 4; i++) {
        const int rbase = m0 + wr + i * 16 + quad * 4;
#pragma unroll
        for (int r = 0; r < 4; r++) {
            const size_t grow = (size_t)row_off + rbase + r;
            const float wt = wts[grow * 3 + scale_idx];
#pragma unroll
            for (int j = 0; j < 4; j++) {
                const int col = col0 + wc + j * 16 + l16;
                const float v = acc[i][j][r] + bias[col];
                if (store_s) Sout[grow * 256 + col] = v;
                float* bp = Blnd + grow * 256 + col;
                if (blend_init) *bp = wt * v;
                else            *bp = *bp + wt * v;
            }
        }
    }
}

// ---------- final squeeze: OUT = [UP | BL] @ sq_w^T + sq_b, K=512 -----------
__global__ __launch_bounds__(256, 2) void gemmf_mfma(
    const float* __restrict__ UP, const float* __restrict__ BLD,
    const ushort* __restrict__ Wth, const ushort* __restrict__ Wtl,  // [256][512]
    const float* __restrict__ SQB, float* __restrict__ OUT)
{
    const int m0 = blockIdx.x * 128;
    const int col0 = blockIdx.y * 128;
    const ushort* wth = Wth + (size_t)col0 * 512;
    const ushort* wtl = Wtl + (size_t)col0 * 512;
    GEMM_DECLS
    for (int k0 = 0; k0 < 512; k0 += 32) {
        const float* Ap = (k0 < 256) ? UP : BLD;
        STAGE_A(Ap, (k0 & 255))
        STAGE_B(wth, wtl, 512, k0)
        __syncthreads();
        GEMM_COMPUTE
        __syncthreads();
    }
#pragma unroll
    for (int j = 0; j < 4; j++) {
        const int col = col0 + wc + j * 16 + l16;
        const float bj = SQB[col];
#pragma unroll
        for (int i = 0; i < 4; i++) {
            const int rbase = m0 + wr + i * 16 + quad * 4;
#pragma unroll
            for (int r = 0; r < 4; r++)
                OUT[(size_t)(rbase + r) * 256 + col] = acc[i][j][r] + bj;
        }
    }
}

// ----------------- windowed multi-head attention (per window) ---------------
template <int WS, int NH>
__global__ __launch_bounds__(256) void win_attn(
    const float* __restrict__ Q, const float* __restrict__ K,
    const float* __restrict__ V, float* __restrict__ CTX)
{
    constexpr int WIN = WS * WS;
    constexpr int NW = 64 / WS;
    constexpr int CW = NH * 32;
    __shared__ float qs[WIN][CW + 4], ks[WIN][CW + 4], vs[WIN][CW + 4];
    __shared__ float sc[NH][WIN][WIN + 1];
    const int tid = threadIdx.x;
    const int wid = blockIdx.x;
    const int b = wid / (NW * NW);
    const int rem = wid % (NW * NW);
    const int p = rem / NW, q = rem % NW;
    const int h0 = blockIdx.y * NH;

    for (int idx = tid; idx < WIN * CW; idx += 256) {
        const int i = idx / CW;
        const int cc = idx % CW;
        const int ti = i / WS, tj = i % WS;
        const size_t g = ((size_t)(b * 4096 + (p * WS + ti) * 64 + (q * WS + tj))) * 256 + h0 * 32 + cc;
        qs[i][cc] = Q[g]; ks[i][cc] = K[g]; vs[i][cc] = V[g];
    }
    __syncthreads();
    const float scale = 0.17677669529663687f;  // 1/sqrt(32)
    for (int idx = tid; idx < NH * WIN * WIN; idx += 256) {
        const int hl = idx / (WIN * WIN);
        const int r = idx % (WIN * WIN);
        const int i = r / WIN, j = r % WIN;
        const int co = hl * 32;
        float s = 0.f;
#pragma unroll
        for (int d = 0; d < 32; d++) s += qs[i][co + d] * ks[j][co + d];
        sc[hl][i][j] = s * scale;
    }
    __syncthreads();
    if (tid < NH * WIN) {
        const int hl = tid / WIN, i = tid % WIN;
        float mx = -3.4e38f;
        for (int j = 0; j < WIN; j++) mx = fmaxf(mx, sc[hl][i][j]);
        float sum = 0.f;
        for (int j = 0; j < WIN; j++) {
            float e = __expf(sc[hl][i][j] - mx);
            sc[hl][i][j] = e; sum += e;
        }
        const float inv = 1.f / sum;
        for (int j = 0; j < WIN; j++) sc[hl][i][j] *= inv;
    }
    __syncthreads();
    for (int idx = tid; idx < WIN * CW; idx += 256) {
        const int i = idx / CW;
        const int cc = idx % CW;
        const int hl = cc >> 5;
        float s = 0.f;
        for (int j = 0; j < WIN; j++) s += sc[hl][i][j] * vs[j][cc];
        const int ti = i / WS, tj = i % WS;
        const size_t g = ((size_t)(b * 4096 + (p * WS + ti) * 64 + (q * WS + tj))) * 256 + h0 * 32 + cc;
        CTX[g] = s;
    }
}

// ----------------------------- edge conv (C->1, 3x3) ------------------------
__global__ __launch_bounds__(256) void edge_conv(
    const float* __restrict__ x, const float* __restrict__ ew, float* __restrict__ edge)
{
    __shared__ float wsm[2304];
    __shared__ float red[4];
    const int bh = blockIdx.x;
    const int b = bh >> 6, h = bh & 63;
    const int tid = threadIdx.x;  // = channel
    for (int i = tid; i < 2304; i += 256) wsm[i] = ew[i];
    __syncthreads();
    float wc[9];
#pragma unroll
    for (int t = 0; t < 9; t++) wc[t] = wsm[tid * 9 + t];

    for (int w = 0; w < 64; w++) {
        float acc = 0.f;
#pragma unroll
        for (int kh = 0; kh < 3; kh++) {
            const int hh = h + kh - 1;
            if ((unsigned)hh > 63u) continue;
#pragma unroll
            for (int kw = 0; kw < 3; kw++) {
                const int ww = w + kw - 1;
                if ((unsigned)ww > 63u) continue;
                acc += x[((size_t)b * 4096 + hh * 64 + ww) * 256 + tid] * wc[kh * 3 + kw];
            }
        }
        for (int off = 32; off; off >>= 1) acc += __shfl_down(acc, off);
        if ((tid & 63) == 0) red[tid >> 6] = acc;
        __syncthreads();
        if (tid == 0)
            edge[(size_t)b * 4096 + h * 64 + w] = fabsf(red[0] + red[1] + red[2] + red[3]);
        __syncthreads();
    }
}

// ---------------- box-average + tiny MLP + 3-way softmax --------------------
__global__ __launch_bounds__(256) void avg_mlp(
    const float* __restrict__ edge, const float* __restrict__ w1, const float* __restrict__ b1,
    const float* __restrict__ w2, const float* __restrict__ b2, float* __restrict__ wts)
{
    const int idx = blockIdx.x * 256 + threadIdx.x;  // 0..65535
    const int b = idx >> 12, rem = idx & 4095, h = rem >> 6, w = rem & 63;
    float s = 0.f;
#pragma unroll
    for (int kh = -1; kh <= 1; kh++) {
        const int hh = h + kh;
        if ((unsigned)hh > 63u) continue;
#pragma unroll
        for (int kw = -1; kw <= 1; kw++) {
            const int ww = w + kw;
            if ((unsigned)ww > 63u) continue;
            s += edge[(size_t)b * 4096 + hh * 64 + ww];
        }
    }
    const float e = s / 9.f;
    float l0 = b2[0], l1 = b2[1], l2 = b2[2];
#pragma unroll
    for (int j = 0; j < 16; j++) {
        float hd = fmaxf(e * w1[j] + b1[j], 0.f);
        l0 += hd * w2[j * 3 + 0];
        l1 += hd * w2[j * 3 + 1];
        l2 += hd * w2[j * 3 + 2];
    }
    const float mx = fmaxf(l0, fmaxf(l1, l2));
    const float e0 = __expf(l0 - mx), e1 = __expf(l1 - mx), e2 = __expf(l2 - mx);
    const float inv = 1.f / (e0 + e1 + e2);
    wts[(size_t)idx * 3 + 0] = e0 * inv;
    wts[(size_t)idx * 3 + 1] = e1 * inv;
    wts[(size_t)idx * 3 + 2] = e2 * inv;
}

// ---------------------- DlightConv token pooling ----------------------------
__global__ __launch_bounds__(256) void dlight(
    const float* __restrict__ S1, const float* __restrict__ dlw,
    const float* __restrict__ dlb, float* __restrict__ XDL)
{
    __shared__ float xw[16][257];
    __shared__ float m[256];
    __shared__ float pr[16];
    __shared__ float pr2[16];
    const int wid = blockIdx.x;  // b*256 + p*16 + q
    const int b = wid >> 8, rem = wid & 255, p = rem >> 4, q = rem & 15;
    const int tid = threadIdx.x;  // channel
#pragma unroll
    for (int t = 0; t < 16; t++) {
        const int ti = t >> 2, tj = t & 3;
        xw[t][tid] = S1[((size_t)b * 4096 + (p * 4 + ti) * 64 + (q * 4 + tj)) * 256 + tid];
    }
    float mm = 0.f;
#pragma unroll
    for (int t = 0; t < 16; t++) mm += xw[t][tid];
    m[tid] = mm * (1.f / 16.f);
    __syncthreads();
    if (tid < 16) {
        float lg = dlb[tid];
        for (int c = 0; c < 256; c++) lg += m[c] * dlw[c * 16 + tid];
        pr[tid] = lg;
    }
    __syncthreads();
    if (tid < 16) {
        float mx = -3.4e38f;
        for (int j = 0; j < 16; j++) mx = fmaxf(mx, pr[j]);
        float sum = 0.f;
        for (int j = 0; j < 16; j++) sum += __expf(pr[j] - mx);
        pr2[tid] = __expf(pr[tid] - mx) / sum;
    }
    __syncthreads();
    float o = 0.f;
#pragma unroll
    for (int t = 0; t < 16; t++) o += xw[t][tid] * pr2[t];
    XDL[(size_t)wid * 256 + tid] = o;
}

// ----------------------------- axial attention ------------------------------
__global__ __launch_bounds__(256) void axial_row(
    const float* __restrict__ Q, const float* __restrict__ K, const float* __restrict__ V,
    const float* __restrict__ gsp, const float* __restrict__ gbp, float* __restrict__ XG)
{
    __shared__ float qs[16][257], ks[16][257], vs[16][257];
    __shared__ float sc[16][17];
    const int bid = blockIdx.x;
    const int b = bid >> 4, r = bid & 15;
    const int tid = threadIdx.x;
    const float gs = gsp[0], gb = gbp[0];
#pragma unroll
    for (int w = 0; w < 16; w++) {
        const size_t base = ((size_t)b * 256 + r * 16 + w) * 256 + tid;
        qs[w][tid] = Q[base]; ks[w][tid] = K[base]; vs[w][tid] = V[base];
    }
    __syncthreads();
    {
        const int w = tid >> 4, vv = tid & 15;
        float s = 0.f;
        for (int c = 0; c < 256; c++) s += qs[w][c] * ks[vv][c];
        const float d = (float)(w - vv);
        sc[w][vv] = s - (gs * d * d + gb);
    }
    __syncthreads();
    if (tid < 16) {
        float mx = -3.4e38f;
        for (int j = 0; j < 16; j++) mx = fmaxf(mx, sc[tid][j]);
        float sum = 0.f;
        for (int j = 0; j < 16; j++) {
            float e = __expf(sc[tid][j] - mx);
            sc[tid][j] = e; sum += e;
        }
        const float inv = 1.f / sum;
        for (int j = 0; j < 16; j++) sc[tid][j] *= inv;
    }
    __syncthreads();
#pragma unroll
    for (int w2 = 0; w2 < 16; w2++) {
        float o = 0.f;
#pragma unroll
        for (int k2 = 0; k2 < 16; k2++) o += sc[w2][k2] * vs[k2][tid];
        XG[((size_t)b * 256 + r * 16 + w2) * 256 + tid] = o;
    }
}

__global__ __launch_bounds__(256) void axial_col(
    const float* __restrict__ Q, const float* __restrict__ K, const float* __restrict__ V,
    const float* __restrict__ gsp, const float* __restrict__ gbp, float* __restrict__ XG)
{
    __shared__ float qs[16][257], ks[16][257], vs[16][257];
    __shared__ float sc[16][17];
    const int bid = blockIdx.x;
    const int b = bid >> 4, col = bid & 15;
    const int tid = threadIdx.x;
    const float gs = gsp[0], gb = gbp[0];
#pragma unroll
    for (int h = 0; h < 16; h++) {
        const size_t base = ((size_t)b * 256 + h * 16 + col) * 256 + tid;
        qs[h][tid] = Q[base]; ks[h][tid] = K[base]; vs[h][tid] = V[base];
    }
    __syncthreads();
    {
        const int r = tid >> 4, vv = tid & 15;
        float s = 0.f;
        for (int c = 0; c < 256; c++) s += qs[r][c] * ks[vv][c];
        const float d = (float)(r - vv);
        sc[r][vv] = s - (gs * d * d + gb);
    }
    __syncthreads();
    if (tid < 16) {
        float mx = -3.4e38f;
        for (int j = 0; j < 16; j++) mx = fmaxf(mx, sc[tid][j]);
        float sum = 0.f;
        for (int j = 0; j < 16; j++) {
            float e = __expf(sc[tid][j] - mx);
            sc[tid][j] = e; sum += e;
        }
        const float inv = 1.f / sum;
        for (int j = 0; j < 16; j++) sc[tid][j] *= inv;
    }
    __syncthreads();
#pragma unroll
    for (int r2 = 0; r2 < 16; r2++) {
        float o = 0.f;
#pragma unroll
        for (int k2 = 0; k2 < 16; k2++) o += sc[r2][k2] * vs[k2][tid];
        XG[((size_t)b * 256 + r2 * 16 + col) * 256 + tid] += o;
    }
}

// -------------------- bilinear upsample 16x16 -> 64x64 ----------------------
__global__ __launch_bounds__(256) void upsample(
    const float* __restrict__ XG, float* __restrict__ UP)
{
    const unsigned idx = blockIdx.x * 256u + threadIdx.x;
    const int c = idx & 255;
    const unsigned t2 = idx >> 8;
    const int w = t2 & 63;
    const unsigned t3 = t2 >> 6;
    const int h = t3 & 63;
    const int b = t3 >> 6;
    const float rr = 15.f / 63.f;
    const float ph = h * rr, pw = w * rr;
    int h0 = (int)floorf(ph); float th = ph - (float)h0; int h1 = min(h0 + 1, 15);
    int w0 = (int)floorf(pw); float tw = pw - (float)w0; int w1 = min(w0 + 1, 15);
    const size_t bb = (size_t)b * 256;
    const float v00 = XG[((bb + h0 * 16 + w0)) * 256 + c];
    const float v10 = XG[((bb + h1 * 16 + w0)) * 256 + c];
    const float v01 = XG[((bb + h0 * 16 + w1)) * 256 + c];
    const float v11 = XG[((bb + h1 * 16 + w1)) * 256 + c];
    const float c0 = v00 * (1.f - th) + v10 * th;
    const float c1 = v01 * (1.f - th) + v11 * th;
    UP[idx] = c0 * (1.f - tw) + c1 * tw;
}

// ---------------------------------------------------------------------------
extern "C" void kernel_launch(void* const* d_in, const int* in_sizes, int n_in,
                              void* d_out, int out_size, void* d_ws, size_t ws_size,
                              hipStream_t stream)
{
    const float* x      = (const float*)d_in[0];
    const float* attn_w = (const float*)d_in[1];
    const float* attn_b = (const float*)d_in[2];
    const float* edge_w = (const float*)d_in[3];
    const float* mlp_w1 = (const float*)d_in[4];
    const float* mlp_b1 = (const float*)d_in[5];
    const float* mlp_w2 = (const float*)d_in[6];
    const float* mlp_b2 = (const float*)d_in[7];
    const float* dl_w   = (const float*)d_in[8];
    const float* dl_b   = (const float*)d_in[9];
    const float* ax_w   = (const float*)d_in[10];
    const float* ax_b   = (const float*)d_in[11];
    const float* g_shift= (const float*)d_in[12];
    const float* g_bias = (const float*)d_in[13];
    const float* sq_w   = (const float*)d_in[14];
    const float* sq_b   = (const float*)d_in[15];
    float* out = (float*)d_out;

    float* ws = (float*)d_ws;
    const size_t MT = 65536;
    float* blend = ws;                       // 16,777,216
    float* s1    = blend + MT * 256;         // 16,777,216
    float* scr   = s1 + MT * 256;            // 16,777,216 (chunk QKV; later `up`)
    float* chQ   = scr;                      // 4,194,304 (also ctx)
    float* chK   = chQ + (size_t)CHUNK_TOK * 256;
    float* chV   = chK + (size_t)CHUNK_TOK * 256;
    float* up    = scr;
    float* edge  = scr + MT * 256;           // 65,536
    float* wts   = edge + 65536;             // 196,608
    float* xdl   = wts + 196608;             // 1,048,576
    float* axq   = xdl + 1048576;
    float* axk   = axq + 1048576;
    float* axv   = axk + 1048576;
    float* xg    = axv + 1048576;
    // split-weight region: 2 x 1,114,112 ushort = 1,114,112 floats
    ushort* Wth = (ushort*)(xg + 1048576);
    ushort* Wtl = Wth + 1114112;
    // total ~227.8 MB

    // ---- pre-split weights: [n][k] bf16 hi/lo -----------------------------
    // mats 0..11: attn (3 scales x 4); 12..14: axial; 15: sq (256x512)
    split_w_kmajor<<<(12 * 65536 + 255) / 256, 256, 0, stream>>>(attn_w, Wth, Wtl, 12);
    split_w_kmajor<<<(3 * 65536 + 255) / 256, 256, 0, stream>>>(
        ax_w, Wth + (size_t)12 * 65536, Wtl + (size_t)12 * 65536, 3);
    split_w_nmajor<<<(131072 + 255) / 256, 256, 0, stream>>>(
        sq_w, Wth + (size_t)15 * 65536, Wtl + (size_t)15 * 65536, 131072);

    // ---- selector weights -------------------------------------------------
    edge_conv<<<1024, 256, 0, stream>>>(x, edge_w, edge);
    avg_mlp<<<256, 256, 0, stream>>>(edge, mlp_w1, mlp_b1, mlp_w2, mlp_b2, wts);

    // ---- three window-attention scales, chunked; blend fused in proj ------
    for (int i = 0; i < 3; i++) {
        const ushort* Wh = Wth + (size_t)i * 4 * 65536;
        const ushort* Wl = Wtl + (size_t)i * 4 * 65536;
        const float* c0 = attn_b + (size_t)(i * 4 + 0) * 256;
        const float* c1 = attn_b + (size_t)(i * 4 + 1) * 256;
        const float* c2 = attn_b + (size_t)(i * 4 + 2) * 256;
        const float* c3 = attn_b + (size_t)(i * 4 + 3) * 256;
        for (int ch = 0; ch < 16 / CHUNK_B; ch++) {
            const size_t toff = (size_t)ch * CHUNK_TOK;
            const float* xc = x + toff * 256;
            gemm3_mfma<<<dim3(CHUNK_TOK / 128, 6), 256, 0, stream>>>(
                xc, Wh, Wl, c0, c1, c2, chQ, chK, chV);
            if (i == 0)
                win_attn<2, 8><<<dim3(CHUNK_B * 32 * 32, 1), 256, 0, stream>>>(chQ, chK, chV, chQ);
            if (i == 1)
                win_attn<4, 4><<<dim3(CHUNK_B * 16 * 16, 2), 256, 0, stream>>>(chQ, chK, chV, chQ);
            if (i == 2)
                win_attn<8, 1><<<dim3(CHUNK_B * 8 * 8, 8), 256, 0, stream>>>(chQ, chK, chV, chQ);
            gemmp_mfma<<<dim3(CHUNK_TOK / 128, 2), 256, 0, stream>>>(
                chQ, Wh + (size_t)3 * 65536, Wl + (size_t)3 * 65536, c3,
                s1, (i == 1) ? 1 : 0, blend, wts, i, (i == 0) ? 1 : 0, (int)toff);
        }
    }

    // ---- DlightConv pooling on s1 -----------------------------------------
    dlight<<<4096, 256, 0, stream>>>(s1, dl_w, dl_b, xdl);

    // ---- axial q,k,v projections (M = 4096) -------------------------------
    gemm3_mfma<<<dim3(4096 / 128, 6), 256, 0, stream>>>(
        xdl, Wth + (size_t)12 * 65536, Wtl + (size_t)12 * 65536,
        ax_b, ax_b + 256, ax_b + 512, axq, axk, axv);
    axial_row<<<256, 256, 0, stream>>>(axq, axk, axv, g_shift, g_bias, xg);
    axial_col<<<256, 256, 0, stream>>>(axq, axk, axv, g_shift, g_bias, xg);

    // ---- upsample 16x16 -> 64x64 into reused scr region -------------------
    upsample<<<65536, 256, 0, stream>>>(xg, up);

    // ---- final squeeze GEMM (K=512) ---------------------------------------
    gemmf_mfma<<<dim3(512, 2), 256, 0, stream>>>(
        up, blend, Wth + (size_t)15 * 65536, Wtl + (size_t)15 * 65536, sq_b, out);
}

// Round 5
// 1298.754 us; speedup vs baseline: 1.7625x; 1.0849x over previous
//
#include <hip/hip_runtime.h>
#include <math.h>

// ---------------------------------------------------------------------------
// CSAttention forward, MI355X. GEMMs via split-bf16 (hi/lo) 3-MFMA emulation:
//   A*B ~= Ah*Bh + Al*Bh + Ah*Bl   (fp32 accumulate, ~16 mantissa bits)
// Layout: token maps (b, h*64+w, c) row-major, C=256, B=16.
// R5: edge_conv factorized into edge_gemm9 (wave-per-pixel inner product,
//     fully parallel) + edge_combine (9-point gather). Old edge_conv was
//     latency-serialized (64 sequential w-iters, 155us @ 7.5% VALUBusy).
// ---------------------------------------------------------------------------

#define CHUNK_B 4
#define CHUNK_TOK (CHUNK_B * 4096)   // 16384 tokens per chunk
#define SA 40                        // LDS k-stride (elements), 80B padded

typedef __attribute__((ext_vector_type(8))) short short8;
typedef __attribute__((ext_vector_type(4))) float f32x4;

__device__ __forceinline__ ushort f2bf(float f) {
    union { float f; unsigned u; } v; v.f = f;
    unsigned r = v.u + 0x7fff + ((v.u >> 16) & 1);
    return (ushort)(r >> 16);
}
__device__ __forceinline__ float bf2f(ushort h) {
    union { unsigned u; float f; } v; v.u = ((unsigned)h) << 16; return v.f;
}
__device__ __forceinline__ void split2(float v, ushort& h, ushort& l) {
    h = f2bf(v);
    l = f2bf(v - bf2f(h));
}

// ---------------- weight pre-split kernels ---------------------------------
__global__ __launch_bounds__(256) void split_w_kmajor(
    const float* __restrict__ W, ushort* __restrict__ Th, ushort* __restrict__ Tl, int nmats)
{
    const int idx = blockIdx.x * 256 + threadIdx.x;
    if (idx >= nmats * 65536) return;
    const int mat = idx >> 16, r = idx & 65535;
    const int n = r >> 8, k = r & 255;
    const float v = W[(size_t)mat * 65536 + k * 256 + n];
    ushort h, l; split2(v, h, l);
    Th[idx] = h; Tl[idx] = l;
}
__global__ __launch_bounds__(256) void split_w_nmajor(
    const float* __restrict__ W, ushort* __restrict__ Th, ushort* __restrict__ Tl, int total)
{
    const int idx = blockIdx.x * 256 + threadIdx.x;
    if (idx >= total) return;
    ushort h, l; split2(W[idx], h, l);
    Th[idx] = h; Tl[idx] = l;
}

// ---------------- MFMA GEMM core pieces (macros for reuse) -----------------
#define GEMM_DECLS                                                            \
    __shared__ ushort Ah[128 * SA], Al[128 * SA], Bh[128 * SA], Bl[128 * SA]; \
    const int tid = threadIdx.x;                                              \
    const int wave = tid >> 6, lane = tid & 63;                               \
    const int quad = lane >> 4, l16 = lane & 15;                              \
    const int wr = (wave >> 1) * 64, wc = (wave & 1) * 64;                    \
    f32x4 acc[4][4];                                                          \
    _Pragma("unroll") for (int i = 0; i < 4; i++)                             \
        _Pragma("unroll") for (int j = 0; j < 4; j++)                         \
            acc[i][j] = (f32x4){0.f, 0.f, 0.f, 0.f};                          \
    const int srow = tid >> 1;            /* 0..127 */                        \
    const int skp  = (tid & 1) * 16;      /* 0 or 16 */

#define STAGE_A(Aptr, kk)                                                     \
    {                                                                         \
        const float* src = (Aptr) + (size_t)(m0 + srow) * 256 + (kk) + skp;   \
        _Pragma("unroll") for (int c = 0; c < 4; c++) {                       \
            float4 v = *(const float4*)(src + c * 4);                         \
            ushort4 h, l;                                                     \
            split2(v.x, h.x, l.x); split2(v.y, h.y, l.y);                     \
            split2(v.z, h.z, l.z); split2(v.w, h.w, l.w);                     \
            *(ushort4*)&Ah[srow * SA + skp + c * 4] = h;                      \
            *(ushort4*)&Al[srow * SA + skp + c * 4] = l;                      \
        }                                                                     \
    }

#define STAGE_B(WthP, WtlP, Kst, k0)                                          \
    {                                                                         \
        const size_t wo = (size_t)(srow) * (Kst) + (k0) + skp;                \
        *(ulonglong2*)&Bh[srow * SA + skp]     = *(const ulonglong2*)((WthP) + wo);     \
        *(ulonglong2*)&Bh[srow * SA + skp + 8] = *(const ulonglong2*)((WthP) + wo + 8); \
        *(ulonglong2*)&Bl[srow * SA + skp]     = *(const ulonglong2*)((WtlP) + wo);     \
        *(ulonglong2*)&Bl[srow * SA + skp + 8] = *(const ulonglong2*)((WtlP) + wo + 8); \
    }

#define GEMM_COMPUTE                                                          \
    {                                                                         \
        short8 afh[4], afl[4], bfh[4], bfl[4];                                \
        _Pragma("unroll") for (int i = 0; i < 4; i++) {                       \
            const int ro = (wr + i * 16 + l16) * SA + quad * 8;               \
            afh[i] = *(const short8*)&Ah[ro];                                 \
            afl[i] = *(const short8*)&Al[ro];                                 \
        }                                                                     \
        _Pragma("unroll") for (int j = 0; j < 4; j++) {                       \
            const int no = (wc + j * 16 + l16) * SA + quad * 8;               \
            bfh[j] = *(const short8*)&Bh[no];                                 \
            bfl[j] = *(const short8*)&Bl[no];                                 \
        }                                                                     \
        _Pragma("unroll") for (int i = 0; i < 4; i++)                         \
            _Pragma("unroll") for (int j = 0; j < 4; j++) {                   \
                acc[i][j] = __builtin_amdgcn_mfma_f32_16x16x32_bf16(          \
                    afh[i], bfh[j], acc[i][j], 0, 0, 0);                      \
                acc[i][j] = __builtin_amdgcn_mfma_f32_16x16x32_bf16(          \
                    afl[i], bfh[j], acc[i][j], 0, 0, 0);                      \
                acc[i][j] = __builtin_amdgcn_mfma_f32_16x16x32_bf16(          \
                    afh[i], bfl[j], acc[i][j], 0, 0, 0);                      \
            }                                                                 \
    }

// ---------- fused 3-matrix GEMM (Q,K,V or axial q,k,v): grid (M/128, 6) -----
__global__ __launch_bounds__(256, 2) void gemm3_mfma(
    const float* __restrict__ A,
    const ushort* __restrict__ Wth, const ushort* __restrict__ Wtl,
    const float* __restrict__ b0, const float* __restrict__ b1, const float* __restrict__ b2,
    float* __restrict__ O0, float* __restrict__ O1, float* __restrict__ O2)
{
    const int m0 = blockIdx.x * 128;
    const int mat = blockIdx.y >> 1;
    const int col0 = (blockIdx.y & 1) * 128;
    const ushort* wth = Wth + (size_t)mat * 65536 + (size_t)col0 * 256;
    const ushort* wtl = Wtl + (size_t)mat * 65536 + (size_t)col0 * 256;
    GEMM_DECLS
    for (int k0 = 0; k0 < 256; k0 += 32) {
        STAGE_A(A, k0)
        STAGE_B(wth, wtl, 256, k0)
        __syncthreads();
        GEMM_COMPUTE
        __syncthreads();
    }
    const float* bias = (mat == 0) ? b0 : (mat == 1) ? b1 : b2;
    float* O = (mat == 0) ? O0 : (mat == 1) ? O1 : O2;
#pragma unroll
    for (int j = 0; j < 4; j++) {
        const int col = col0 + wc + j * 16 + l16;
        const float bj = bias[col];
#pragma unroll
        for (int i = 0; i < 4; i++) {
            const int rbase = m0 + wr + i * 16 + quad * 4;
#pragma unroll
            for (int r = 0; r < 4; r++)
                O[(size_t)(rbase + r) * 256 + col] = acc[i][j][r] + bj;
        }
    }
}

// ---------- out-projection GEMM with fused blend: grid (M/128, 2) -----------
__global__ __launch_bounds__(256, 2) void gemmp_mfma(
    const float* __restrict__ A,
    const ushort* __restrict__ Wth, const ushort* __restrict__ Wtl,
    const float* __restrict__ bias,
    float* __restrict__ Sout, int store_s,
    float* __restrict__ Blnd, const float* __restrict__ wts, int scale_idx, int blend_init,
    int row_off)
{
    const int m0 = blockIdx.x * 128;
    const int col0 = blockIdx.y * 128;
    const ushort* wth = Wth + (size_t)col0 * 256;
    const ushort* wtl = Wtl + (size_t)col0 * 256;
    GEMM_DECLS
    for (int k0 = 0; k0 < 256; k0 += 32) {
        STAGE_A(A, k0)
        STAGE_B(wth, wtl, 256, k0)
        __syncthreads();
        GEMM_COMPUTE
        __syncthreads();
    }
#pragma unroll
    for (int i = 0; i < 4; i++) {
        const int rbase = m0 + wr + i * 16 + quad * 4;
#pragma unroll
        for (int r = 0; r < 4; r++) {
            const size_t grow = (size_t)row_off + rbase + r;
            const float wt = wts[grow * 3 + scale_idx];
#pragma unroll
            for (int j = 0; j < 4; j++) {
                const int col = col0 + wc + j * 16 + l16;
                const float v = acc[i][j][r] + bias[col];
                if (store_s) Sout[grow * 256 + col] = v;
                float* bp = Blnd + grow * 256 + col;
                if (blend_init) *bp = wt * v;
                else            *bp = *bp + wt * v;
            }
        }
    }
}

// ---------- final squeeze: OUT = [UP | BL] @ sq_w^T + sq_b, K=512 -----------
__global__ __launch_bounds__(256, 2) void gemmf_mfma(
    const float* __restrict__ UP, const float* __restrict__ BLD,
    const ushort* __restrict__ Wth, const ushort* __restrict__ Wtl,
    const float* __restrict__ SQB, float* __restrict__ OUT)
{
    const int m0 = blockIdx.x * 128;
    const int col0 = blockIdx.y * 128;
    const ushort* wth = Wth + (size_t)col0 * 512;
    const ushort* wtl = Wtl + (size_t)col0 * 512;
    GEMM_DECLS
    for (int k0 = 0; k0 < 512; k0 += 32) {
        const float* Ap = (k0 < 256) ? UP : BLD;
        STAGE_A(Ap, (k0 & 255))
        STAGE_B(wth, wtl, 512, k0)
        __syncthreads();
        GEMM_COMPUTE
        __syncthreads();
    }
#pragma unroll
    for (int j = 0; j < 4; j++) {
        const int col = col0 + wc + j * 16 + l16;
        const float bj = SQB[col];
#pragma unroll
        for (int i = 0; i < 4; i++) {
            const int rbase = m0 + wr + i * 16 + quad * 4;
#pragma unroll
            for (int r = 0; r < 4; r++)
                OUT[(size_t)(rbase + r) * 256 + col] = acc[i][j][r] + bj;
        }
    }
}

// ----------------- windowed multi-head attention (per window) ---------------
template <int WS, int NH>
__global__ __launch_bounds__(256) void win_attn(
    const float* __restrict__ Q, const float* __restrict__ K,
    const float* __restrict__ V, float* __restrict__ CTX)
{
    constexpr int WIN = WS * WS;
    constexpr int NW = 64 / WS;
    constexpr int CW = NH * 32;
    __shared__ float qs[WIN][CW + 4], ks[WIN][CW + 4], vs[WIN][CW + 4];
    __shared__ float sc[NH][WIN][WIN + 1];
    const int tid = threadIdx.x;
    const int wid = blockIdx.x;
    const int b = wid / (NW * NW);
    const int rem = wid % (NW * NW);
    const int p = rem / NW, q = rem % NW;
    const int h0 = blockIdx.y * NH;

    for (int idx = tid; idx < WIN * CW; idx += 256) {
        const int i = idx / CW;
        const int cc = idx % CW;
        const int ti = i / WS, tj = i % WS;
        const size_t g = ((size_t)(b * 4096 + (p * WS + ti) * 64 + (q * WS + tj))) * 256 + h0 * 32 + cc;
        qs[i][cc] = Q[g]; ks[i][cc] = K[g]; vs[i][cc] = V[g];
    }
    __syncthreads();
    const float scale = 0.17677669529663687f;  // 1/sqrt(32)
    for (int idx = tid; idx < NH * WIN * WIN; idx += 256) {
        const int hl = idx / (WIN * WIN);
        const int r = idx % (WIN * WIN);
        const int i = r / WIN, j = r % WIN;
        const int co = hl * 32;
        float s = 0.f;
#pragma unroll
        for (int d = 0; d < 32; d++) s += qs[i][co + d] * ks[j][co + d];
        sc[hl][i][j] = s * scale;
    }
    __syncthreads();
    if (tid < NH * WIN) {
        const int hl = tid / WIN, i = tid % WIN;
        float mx = -3.4e38f;
        for (int j = 0; j < WIN; j++) mx = fmaxf(mx, sc[hl][i][j]);
        float sum = 0.f;
        for (int j = 0; j < WIN; j++) {
            float e = __expf(sc[hl][i][j] - mx);
            sc[hl][i][j] = e; sum += e;
        }
        const float inv = 1.f / sum;
        for (int j = 0; j < WIN; j++) sc[hl][i][j] *= inv;
    }
    __syncthreads();
    for (int idx = tid; idx < WIN * CW; idx += 256) {
        const int i = idx / CW;
        const int cc = idx % CW;
        const int hl = cc >> 5;
        float s = 0.f;
        for (int j = 0; j < WIN; j++) s += sc[hl][i][j] * vs[j][cc];
        const int ti = i / WS, tj = i % WS;
        const size_t g = ((size_t)(b * 4096 + (p * WS + ti) * 64 + (q * WS + tj))) * 256 + h0 * 32 + cc;
        CTX[g] = s;
    }
}

// -------- edge conv phase 1: y[p][t] = sum_c x[p][c] * ew[c][t] -------------
// Wave per pixel; lane holds 4 consecutive channels (float4 coalesced load).
__global__ __launch_bounds__(256) void edge_gemm9(
    const float* __restrict__ x, const float* __restrict__ ew, float* __restrict__ ytmp)
{
    __shared__ float wsm[2304];   // ew[c*9 + t]
    const int tid = threadIdx.x;
    for (int i = tid; i < 2304; i += 256) wsm[i] = ew[i];
    __syncthreads();
    const int wave = tid >> 6, lane = tid & 63;
    const int p = blockIdx.x * 4 + wave;            // pixel index 0..65535
    const float4 xv = *(const float4*)(x + (size_t)p * 256 + lane * 4);
    float acc[9];
#pragma unroll
    for (int t = 0; t < 9; t++) acc[t] = 0.f;
    const float xs[4] = {xv.x, xv.y, xv.z, xv.w};
#pragma unroll
    for (int i = 0; i < 4; i++) {
        const int c = lane * 4 + i;
#pragma unroll
        for (int t = 0; t < 9; t++)
            acc[t] = fmaf(xs[i], wsm[c * 9 + t], acc[t]);
    }
#pragma unroll
    for (int t = 0; t < 9; t++) {
#pragma unroll
        for (int off = 1; off < 64; off <<= 1)
            acc[t] += __shfl_xor(acc[t], off);
    }
    if (lane < 9) {
        float v = acc[0];
        switch (lane) {
            case 1: v = acc[1]; break; case 2: v = acc[2]; break;
            case 3: v = acc[3]; break; case 4: v = acc[4]; break;
            case 5: v = acc[5]; break; case 6: v = acc[6]; break;
            case 7: v = acc[7]; break; case 8: v = acc[8]; break;
            default: break;
        }
        ytmp[(size_t)p * 9 + lane] = v;
    }
}

// -------- edge conv phase 2: edge[h,w] = |sum_t y[h+dh,w+dw][t]| ------------
__global__ __launch_bounds__(256) void edge_combine(
    const float* __restrict__ ytmp, float* __restrict__ edge)
{
    const int idx = blockIdx.x * 256 + threadIdx.x;   // 0..65535
    const int b = idx >> 12, rem = idx & 4095, h = rem >> 6, w = rem & 63;
    float s = 0.f;
#pragma unroll
    for (int kh = 0; kh < 3; kh++) {
        const int hh = h + kh - 1;
        if ((unsigned)hh > 63u) continue;
#pragma unroll
        for (int kw = 0; kw < 3; kw++) {
            const int ww = w + kw - 1;
            if ((unsigned)ww > 63u) continue;
            s += ytmp[((size_t)b * 4096 + hh * 64 + ww) * 9 + kh * 3 + kw];
        }
    }
    edge[idx] = fabsf(s);
}

// ---------------- box-average + tiny MLP + 3-way softmax --------------------
__global__ __launch_bounds__(256) void avg_mlp(
    const float* __restrict__ edge, const float* __restrict__ w1, const float* __restrict__ b1,
    const float* __restrict__ w2, const float* __restrict__ b2, float* __restrict__ wts)
{
    const int idx = blockIdx.x * 256 + threadIdx.x;  // 0..65535
    const int b = idx >> 12, rem = idx & 4095, h = rem >> 6, w = rem & 63;
    float s = 0.f;
#pragma unroll
    for (int kh = -1; kh <= 1; kh++) {
        const int hh = h + kh;
        if ((unsigned)hh > 63u) continue;
#pragma unroll
        for (int kw = -1; kw <= 1; kw++) {
            const int ww = w + kw;
            if ((unsigned)ww > 63u) continue;
            s += edge[(size_t)b * 4096 + hh * 64 + ww];
        }
    }
    const float e = s / 9.f;
    float l0 = b2[0], l1 = b2[1], l2 = b2[2];
#pragma unroll
    for (int j = 0; j < 16; j++) {
        float hd = fmaxf(e * w1[j] + b1[j], 0.f);
        l0 += hd * w2[j * 3 + 0];
        l1 += hd * w2[j * 3 + 1];
        l2 += hd * w2[j * 3 + 2];
    }
    const float mx = fmaxf(l0, fmaxf(l1, l2));
    const float e0 = __expf(l0 - mx), e1 = __expf(l1 - mx), e2 = __expf(l2 - mx);
    const float inv = 1.f / (e0 + e1 + e2);
    wts[(size_t)idx * 3 + 0] = e0 * inv;
    wts[(size_t)idx * 3 + 1] = e1 * inv;
    wts[(size_t)idx * 3 + 2] = e2 * inv;
}

// ---------------------- DlightConv token pooling ----------------------------
__global__ __launch_bounds__(256) void dlight(
    const float* __restrict__ S1, const float* __restrict__ dlw,
    const float* __restrict__ dlb, float* __restrict__ XDL)
{
    __shared__ float xw[16][257];
    __shared__ float m[256];
    __shared__ float pr[16];
    __shared__ float pr2[16];
    const int wid = blockIdx.x;  // b*256 + p*16 + q
    const int b = wid >> 8, rem = wid & 255, p = rem >> 4, q = rem & 15;
    const int tid = threadIdx.x;  // channel
#pragma unroll
    for (int t = 0; t < 16; t++) {
        const int ti = t >> 2, tj = t & 3;
        xw[t][tid] = S1[((size_t)b * 4096 + (p * 4 + ti) * 64 + (q * 4 + tj)) * 256 + tid];
    }
    float mm = 0.f;
#pragma unroll
    for (int t = 0; t < 16; t++) mm += xw[t][tid];
    m[tid] = mm * (1.f / 16.f);
    __syncthreads();
    if (tid < 16) {
        float lg = dlb[tid];
        for (int c = 0; c < 256; c++) lg += m[c] * dlw[c * 16 + tid];
        pr[tid] = lg;
    }
    __syncthreads();
    if (tid < 16) {
        float mx = -3.4e38f;
        for (int j = 0; j < 16; j++) mx = fmaxf(mx, pr[j]);
        float sum = 0.f;
        for (int j = 0; j < 16; j++) sum += __expf(pr[j] - mx);
        pr2[tid] = __expf(pr[tid] - mx) / sum;
    }
    __syncthreads();
    float o = 0.f;
#pragma unroll
    for (int t = 0; t < 16; t++) o += xw[t][tid] * pr2[t];
    XDL[(size_t)wid * 256 + tid] = o;
}

// ----------------------------- axial attention ------------------------------
__global__ __launch_bounds__(256) void axial_row(
    const float* __restrict__ Q, const float* __restrict__ K, const float* __restrict__ V,
    const float* __restrict__ gsp, const float* __restrict__ gbp, float* __restrict__ XG)
{
    __shared__ float qs[16][257], ks[16][257], vs[16][257];
    __shared__ float sc[16][17];
    const int bid = blockIdx.x;
    const int b = bid >> 4, r = bid & 15;
    const int tid = threadIdx.x;
    const float gs = gsp[0], gb = gbp[0];
#pragma unroll
    for (int w = 0; w < 16; w++) {
        const size_t base = ((size_t)b * 256 + r * 16 + w) * 256 + tid;
        qs[w][tid] = Q[base]; ks[w][tid] = K[base]; vs[w][tid] = V[base];
    }
    __syncthreads();
    {
        const int w = tid >> 4, vv = tid & 15;
        float s = 0.f;
        for (int c = 0; c < 256; c++) s += qs[w][c] * ks[vv][c];
        const float d = (float)(w - vv);
        sc[w][vv] = s - (gs * d * d + gb);
    }
    __syncthreads();
    if (tid < 16) {
        float mx = -3.4e38f;
        for (int j = 0; j < 16; j++) mx = fmaxf(mx, sc[tid][j]);
        float sum = 0.f;
        for (int j = 0; j < 16; j++) {
            float e = __expf(sc[tid][j] - mx);
            sc[tid][j] = e; sum += e;
        }
        const float inv = 1.f / sum;
        for (int j = 0; j < 16; j++) sc[tid][j] *= inv;
    }
    __syncthreads();
#pragma unroll
    for (int w2 = 0; w2 < 16; w2++) {
        float o = 0.f;
#pragma unroll
        for (int k2 = 0; k2 < 16; k2++) o += sc[w2][k2] * vs[k2][tid];
        XG[((size_t)b * 256 + r * 16 + w2) * 256 + tid] = o;
    }
}

__global__ __launch_bounds__(256) void axial_col(
    const float* __restrict__ Q, const float* __restrict__ K, const float* __restrict__ V,
    const float* __restrict__ gsp, const float* __restrict__ gbp, float* __restrict__ XG)
{
    __shared__ float qs[16][257], ks[16][257], vs[16][257];
    __shared__ float sc[16][17];
    const int bid = blockIdx.x;
    const int b = bid >> 4, col = bid & 15;
    const int tid = threadIdx.x;
    const float gs = gsp[0], gb = gbp[0];
#pragma unroll
    for (int h = 0; h < 16; h++) {
        const size_t base = ((size_t)b * 256 + h * 16 + col) * 256 + tid;
        qs[h][tid] = Q[base]; ks[h][tid] = K[base]; vs[h][tid] = V[base];
    }
    __syncthreads();
    {
        const int r = tid >> 4, vv = tid & 15;
        float s = 0.f;
        for (int c = 0; c < 256; c++) s += qs[r][c] * ks[vv][c];
        const float d = (float)(r - vv);
        sc[r][vv] = s - (gs * d * d + gb);
    }
    __syncthreads();
    if (tid < 16) {
        float mx = -3.4e38f;
        for (int j = 0; j < 16; j++) mx = fmaxf(mx, sc[tid][j]);
        float sum = 0.f;
        for (int j = 0; j < 16; j++) {
            float e = __expf(sc[tid][j] - mx);
            sc[tid][j] = e; sum += e;
        }
        const float inv = 1.f / sum;
        for (int j = 0; j < 16; j++) sc[tid][j] *= inv;
    }
    __syncthreads();
#pragma unroll
    for (int r2 = 0; r2 < 16; r2++) {
        float o = 0.f;
#pragma unroll
        for (int k2 = 0; k2 < 16; k2++) o += sc[r2][k2] * vs[k2][tid];
        XG[((size_t)b * 256 + r2 * 16 + col) * 256 + tid] += o;
    }
}

// -------------------- bilinear upsample 16x16 -> 64x64 ----------------------
__global__ __launch_bounds__(256) void upsample(
    const float* __restrict__ XG, float* __restrict__ UP)
{
    const unsigned idx = blockIdx.x * 256u + threadIdx.x;
    const int c = idx & 255;
    const unsigned t2 = idx >> 8;
    const int w = t2 & 63;
    const unsigned t3 = t2 >> 6;
    const int h = t3 & 63;
    const int b = t3 >> 6;
    const float rr = 15.f / 63.f;
    const float ph = h * rr, pw = w * rr;
    int h0 = (int)floorf(ph); float th = ph - (float)h0; int h1 = min(h0 + 1, 15);
    int w0 = (int)floorf(pw); float tw = pw - (float)w0; int w1 = min(w0 + 1, 15);
    const size_t bb = (size_t)b * 256;
    const float v00 = XG[((bb + h0 * 16 + w0)) * 256 + c];
    const float v10 = XG[((bb + h1 * 16 + w0)) * 256 + c];
    const float v01 = XG[((bb + h0 * 16 + w1)) * 256 + c];
    const float v11 = XG[((bb + h1 * 16 + w1)) * 256 + c];
    const float c0 = v00 * (1.f - th) + v10 * th;
    const float c1 = v01 * (1.f - th) + v11 * th;
    UP[idx] = c0 * (1.f - tw) + c1 * tw;
}

// ---------------------------------------------------------------------------
extern "C" void kernel_launch(void* const* d_in, const int* in_sizes, int n_in,
                              void* d_out, int out_size, void* d_ws, size_t ws_size,
                              hipStream_t stream)
{
    const float* x      = (const float*)d_in[0];
    const float* attn_w = (const float*)d_in[1];
    const float* attn_b = (const float*)d_in[2];
    const float* edge_w = (const float*)d_in[3];
    const float* mlp_w1 = (const float*)d_in[4];
    const float* mlp_b1 = (const float*)d_in[5];
    const float* mlp_w2 = (const float*)d_in[6];
    const float* mlp_b2 = (const float*)d_in[7];
    const float* dl_w   = (const float*)d_in[8];
    const float* dl_b   = (const float*)d_in[9];
    const float* ax_w   = (const float*)d_in[10];
    const float* ax_b   = (const float*)d_in[11];
    const float* g_shift= (const float*)d_in[12];
    const float* g_bias = (const float*)d_in[13];
    const float* sq_w   = (const float*)d_in[14];
    const float* sq_b   = (const float*)d_in[15];
    float* out = (float*)d_out;

    float* ws = (float*)d_ws;
    const size_t MT = 65536;
    float* blend = ws;                       // 16,777,216
    float* s1    = blend + MT * 256;         // 16,777,216
    float* scr   = s1 + MT * 256;            // 16,777,216 (ytmp / chunk QKV / up)
    float* chQ   = scr;                      // 4,194,304 (also ctx)
    float* chK   = chQ + (size_t)CHUNK_TOK * 256;
    float* chV   = chK + (size_t)CHUNK_TOK * 256;
    float* up    = scr;
    float* ytmp  = scr;                      // 589,824 floats, dead before chQ use
    float* edge  = scr + MT * 256;           // 65,536
    float* wts   = edge + 65536;             // 196,608
    float* xdl   = wts + 196608;             // 1,048,576
    float* axq   = xdl + 1048576;
    float* axk   = axq + 1048576;
    float* axv   = axk + 1048576;
    float* xg    = axv + 1048576;
    ushort* Wth = (ushort*)(xg + 1048576);
    ushort* Wtl = Wth + 1114112;

    // ---- pre-split weights: [n][k] bf16 hi/lo -----------------------------
    split_w_kmajor<<<(12 * 65536 + 255) / 256, 256, 0, stream>>>(attn_w, Wth, Wtl, 12);
    split_w_kmajor<<<(3 * 65536 + 255) / 256, 256, 0, stream>>>(
        ax_w, Wth + (size_t)12 * 65536, Wtl + (size_t)12 * 65536, 3);
    split_w_nmajor<<<(131072 + 255) / 256, 256, 0, stream>>>(
        sq_w, Wth + (size_t)15 * 65536, Wtl + (size_t)15 * 65536, 131072);

    // ---- selector weights (factorized edge conv) --------------------------
    edge_gemm9<<<16384, 256, 0, stream>>>(x, edge_w, ytmp);
    edge_combine<<<256, 256, 0, stream>>>(ytmp, edge);
    avg_mlp<<<256, 256, 0, stream>>>(edge, mlp_w1, mlp_b1, mlp_w2, mlp_b2, wts);

    // ---- three window-attention scales, chunked; blend fused in proj ------
    for (int i = 0; i < 3; i++) {
        const ushort* Wh = Wth + (size_t)i * 4 * 65536;
        const ushort* Wl = Wtl + (size_t)i * 4 * 65536;
        const float* c0 = attn_b + (size_t)(i * 4 + 0) * 256;
        const float* c1 = attn_b + (size_t)(i * 4 + 1) * 256;
        const float* c2 = attn_b + (size_t)(i * 4 + 2) * 256;
        const float* c3 = attn_b + (size_t)(i * 4 + 3) * 256;
        for (int ch = 0; ch < 16 / CHUNK_B; ch++) {
            const size_t toff = (size_t)ch * CHUNK_TOK;
            const float* xc = x + toff * 256;
            gemm3_mfma<<<dim3(CHUNK_TOK / 128, 6), 256, 0, stream>>>(
                xc, Wh, Wl, c0, c1, c2, chQ, chK, chV);
            if (i == 0)
                win_attn<2, 8><<<dim3(CHUNK_B * 32 * 32, 1), 256, 0, stream>>>(chQ, chK, chV, chQ);
            if (i == 1)
                win_attn<4, 4><<<dim3(CHUNK_B * 16 * 16, 2), 256, 0, stream>>>(chQ, chK, chV, chQ);
            if (i == 2)
                win_attn<8, 1><<<dim3(CHUNK_B * 8 * 8, 8), 256, 0, stream>>>(chQ, chK, chV, chQ);
            gemmp_mfma<<<dim3(CHUNK_TOK / 128, 2), 256, 0, stream>>>(
                chQ, Wh + (size_t)3 * 65536, Wl + (size_t)3 * 65536, c3,
                s1, (i == 1) ? 1 : 0, blend, wts, i, (i == 0) ? 1 : 0, (int)toff);
        }
    }

    // ---- DlightConv pooling on s1 -----------------------------------------
    dlight<<<4096, 256, 0, stream>>>(s1, dl_w, dl_b, xdl);

    // ---- axial q,k,v projections (M = 4096) -------------------------------
    gemm3_mfma<<<dim3(4096 / 128, 6), 256, 0, stream>>>(
        xdl, Wth + (size_t)12 * 65536, Wtl + (size_t)12 * 65536,
        ax_b, ax_b + 256, ax_b + 512, axq, axk, axv);
    axial_row<<<256, 256, 0, stream>>>(axq, axk, axv, g_shift, g_bias, xg);
    axial_col<<<256, 256, 0, stream>>>(axq, axk, axv, g_shift, g_bias, xg);

    // ---- upsample 16x16 -> 64x64 into reused scr region -------------------
    upsample<<<65536, 256, 0, stream>>>(xg, up);

    // ---- final squeeze GEMM (K=512) ---------------------------------------
    gemmf_mfma<<<dim3(512, 2), 256, 0, stream>>>(
        up, blend, Wth + (size_t)15 * 65536, Wtl + (size_t)15 * 65536, sq_b, out);
}